// Round 6
// baseline (2655.965 us; speedup 1.0000x reference)
//
#include <hip/hip_runtime.h>

typedef __attribute__((ext_vector_type(8))) __bf16 bf16x8;
typedef __attribute__((ext_vector_type(4))) float f32x4;

#define MFMA16(a, b, c) __builtin_amdgcn_mfma_f32_16x16x32_bf16(a, b, c, 0, 0, 0)

#define T_SEQ 512
#define F_IN 32
#define H1 128
#define E2 64

__device__ __forceinline__ float bf2f(ushort u) {
    union { uint i; float f; } v; v.i = ((uint)u) << 16; return v.f;
}
__device__ __forceinline__ ushort f2bf(float f) {
    union { float f; uint i; } v; v.f = f;
    uint r = v.i + 0x7fffu + ((v.i >> 16) & 1u);
    return (ushort)(r >> 16);
}
__device__ __forceinline__ float fast_sigmoid(float x) {
    float e = __expf(-x);
    return __builtin_amdgcn_rcpf(1.0f + e);
}
__device__ __forceinline__ float fast_tanh(float x) {
    float e = __expf(-2.0f * x);
    return 2.0f * __builtin_amdgcn_rcpf(1.0f + e) - 1.0f;
}
__device__ __forceinline__ bf16x8 load_w8(const float* p) {
    bf16x8 r;
#pragma unroll
    for (int j = 0; j < 8; ++j) r[j] = (__bf16)p[j];
    return r;
}

// Fused 2-layer LSTM. 32 blocks x 256 threads; block owns 16 batch rows for
// the FULL sequence, both layers. fp32 inputs (proven round 4), fp32 OUTPUT
// (harness contract: reference output dtype = float32).
// Split-precision (hi+lo bf16) carried for x, h1, h2 -> only weight-bf16
// quantization error remains (~1e-3 << 3.9e-3 threshold).
__global__ __launch_bounds__(256, 1) void lstm_fused(
    const float* __restrict__ x,      // [512][512][32]
    const float* __restrict__ Wih1,   // [512][32]
    const float* __restrict__ Whh1,   // [512][128]
    const float* __restrict__ bih1,   // [512]
    const float* __restrict__ bhh1,   // [512]
    const float* __restrict__ Wih2,   // [256][128]
    const float* __restrict__ Whh2,   // [256][64]
    const float* __restrict__ bih2,   // [256]
    const float* __restrict__ bhh2,   // [256]
    float* __restrict__ out)          // [512][64] fp32
{
    __shared__ ushort xs [16][72];    // x(t): cols 0..31 hi, 32..63 lo
    __shared__ ushort h1s[16][264];   // h1: cols 0..127 hi, 128..255 lo
    __shared__ ushort h2s[16][136];   // h2: cols 0..63 hi, 64..127 lo
    __shared__ float  g1 [16][516];   // layer-1 activated gates
    __shared__ float  g2 [16][260];   // layer-2 activated gates

    const int tid  = threadIdx.x;
    const int wave = tid >> 6;
    const int lane = tid & 63;
    const int l15  = lane & 15;
    const int quad = lane >> 4;
    const int r0   = blockIdx.x * 16;

    // ---- weights -> registers (B-frag: lane holds col n=l15, k=quad*8+j) ----
    bf16x8 w1h[4][8];   // L1 recurrent K=128: 4 k-tiles x 8 n-tiles
    bf16x8 w1x[8];      // L1 input K=32
    float  b1[8];
#pragma unroll
    for (int nt = 0; nt < 8; ++nt) {
        const int n = wave * 128 + nt * 16 + l15;
#pragma unroll
        for (int kt = 0; kt < 4; ++kt)
            w1h[kt][nt] = load_w8(Whh1 + n * H1 + kt * 32 + quad * 8);
        w1x[nt] = load_w8(Wih1 + n * F_IN + quad * 8);
        b1[nt]  = bih1[n] + bhh1[n];
    }
    bf16x8 w2x[4][4];   // L2 input K=128
    bf16x8 w2h[2][4];   // L2 recurrent K=64
    float  b2[4];
#pragma unroll
    for (int nt = 0; nt < 4; ++nt) {
        const int n = wave * 64 + nt * 16 + l15;
#pragma unroll
        for (int kt = 0; kt < 4; ++kt)
            w2x[kt][nt] = load_w8(Wih2 + n * H1 + kt * 32 + quad * 8);
#pragma unroll
        for (int kt = 0; kt < 2; ++kt)
            w2h[kt][nt] = load_w8(Whh2 + n * E2 + kt * 32 + quad * 8);
        b2[nt] = bih2[n] + bhh2[n];
    }

    // zero h states (hi + lo planes)
    for (int i = tid; i < 16 * 264; i += 256) ((ushort*)h1s)[i] = 0;
    for (int i = tid; i < 16 * 136; i += 256) ((ushort*)h2s)[i] = 0;

    // per-thread cell states (fp32, never quantized)
    const int erow = tid >> 4;
    const int ec1  = (tid & 15) * 8;   // layer-1: 8 units/thread
    const int ec2  = (tid & 15) * 4;   // layer-2: 4 units/thread
    float c1[8], c2[4];
#pragma unroll
    for (int j = 0; j < 8; ++j) c1[j] = 0.0f;
#pragma unroll
    for (int j = 0; j < 4; ++j) c2[j] = 0.0f;

    __syncthreads();

    for (int t = 0; t < T_SEQ; ++t) {
        // ---- stage x(t): 16 rows x 32 f32 -> hi/lo bf16; thread: 2 elems ----
        {
            const int row = tid >> 4, cc = (tid & 15) * 2;
            const float2 v = *(const float2*)(x +
                              ((size_t)(r0 + row) * T_SEQ + t) * F_IN + cc);
            const ushort h0 = f2bf(v.x), h1v = f2bf(v.y);
            const ushort l0 = f2bf(v.x - bf2f(h0));
            const ushort l1 = f2bf(v.y - bf2f(h1v));
            *(uint*)&xs[row][cc]      = (uint)h0 | ((uint)h1v << 16);
            *(uint*)&xs[row][32 + cc] = (uint)l0 | ((uint)l1 << 16);
        }
        __syncthreads();   // B1: xs ready; h1s(t-1) stable

        // ---- layer-1 gates = b1 + (x_hi+x_lo) Wih1^T + (h1_hi+h1_lo) Whh1^T
        {
            f32x4 acc[8];
#pragma unroll
            for (int nt = 0; nt < 8; ++nt)
                acc[nt] = (f32x4){b1[nt], b1[nt], b1[nt], b1[nt]};
#pragma unroll
            for (int xt = 0; xt < 2; ++xt) {   // 0 = hi, 1 = lo
                const bf16x8 ax = *(const bf16x8*)&xs[l15][xt * 32 + quad * 8];
#pragma unroll
                for (int nt = 0; nt < 8; ++nt)
                    acc[nt] = MFMA16(ax, w1x[nt], acc[nt]);
            }
#pragma unroll
            for (int kt = 0; kt < 8; ++kt) {   // k-tiles 0..3 = hi, 4..7 = lo
                const bf16x8 ah = *(const bf16x8*)&h1s[l15][kt * 32 + quad * 8];
#pragma unroll
                for (int nt = 0; nt < 8; ++nt)
                    acc[nt] = MFMA16(ah, w1h[kt & 3][nt], acc[nt]);
            }
#pragma unroll
            for (int nt = 0; nt < 8; ++nt) {
#pragma unroll
                for (int r = 0; r < 4; ++r) {
                    float v = acc[nt][r];
                    v = (wave == 2) ? fast_tanh(v) : fast_sigmoid(v);
                    g1[quad * 4 + r][wave * 128 + nt * 16 + l15] = v;
                }
            }
        }
        __syncthreads();   // B2: g1 ready; h1s MFMA reads done

        // ---- layer-1 epilogue: c1/h1 update, h1(t) hi/lo -> LDS ----
        {
            float iv[8], fv[8], gv[8], ov[8];
            *(float4*)&iv[0] = *(const float4*)&g1[erow][ec1];
            *(float4*)&iv[4] = *(const float4*)&g1[erow][ec1 + 4];
            *(float4*)&fv[0] = *(const float4*)&g1[erow][128 + ec1];
            *(float4*)&fv[4] = *(const float4*)&g1[erow][128 + ec1 + 4];
            *(float4*)&gv[0] = *(const float4*)&g1[erow][256 + ec1];
            *(float4*)&gv[4] = *(const float4*)&g1[erow][256 + ec1 + 4];
            *(float4*)&ov[0] = *(const float4*)&g1[erow][384 + ec1];
            *(float4*)&ov[4] = *(const float4*)&g1[erow][384 + ec1 + 4];
            ushort hi[8], lo[8];
#pragma unroll
            for (int j = 0; j < 8; ++j) {
                const float cn = fv[j] * c1[j] + iv[j] * gv[j];
                c1[j] = cn;
                const float h = ov[j] * fast_tanh(cn);
                hi[j] = f2bf(h);
                lo[j] = f2bf(h - bf2f(hi[j]));
            }
            uint4 ph, pl;
            ph.x = (uint)hi[0] | ((uint)hi[1] << 16);
            ph.y = (uint)hi[2] | ((uint)hi[3] << 16);
            ph.z = (uint)hi[4] | ((uint)hi[5] << 16);
            ph.w = (uint)hi[6] | ((uint)hi[7] << 16);
            pl.x = (uint)lo[0] | ((uint)lo[1] << 16);
            pl.y = (uint)lo[2] | ((uint)lo[3] << 16);
            pl.z = (uint)lo[4] | ((uint)lo[5] << 16);
            pl.w = (uint)lo[6] | ((uint)lo[7] << 16);
            *(uint4*)&h1s[erow][ec1]       = ph;
            *(uint4*)&h1s[erow][128 + ec1] = pl;
        }
        __syncthreads();   // B3: h1s(t) ready; g1 reads done

        // ---- layer-2 gates = b2 + (h1_hi+h1_lo) Wih2^T + (h2_hi+h2_lo) Whh2^T
        {
            f32x4 acc[4];
#pragma unroll
            for (int nt = 0; nt < 4; ++nt)
                acc[nt] = (f32x4){b2[nt], b2[nt], b2[nt], b2[nt]};
#pragma unroll
            for (int kt = 0; kt < 8; ++kt) {   // 0..3 hi, 4..7 lo
                const bf16x8 a = *(const bf16x8*)&h1s[l15][kt * 32 + quad * 8];
#pragma unroll
                for (int nt = 0; nt < 4; ++nt)
                    acc[nt] = MFMA16(a, w2x[kt & 3][nt], acc[nt]);
            }
#pragma unroll
            for (int kt = 0; kt < 4; ++kt) {   // 0..1 hi, 2..3 lo
                const bf16x8 a = *(const bf16x8*)&h2s[l15][kt * 32 + quad * 8];
#pragma unroll
                for (int nt = 0; nt < 4; ++nt)
                    acc[nt] = MFMA16(a, w2h[kt & 1][nt], acc[nt]);
            }
#pragma unroll
            for (int nt = 0; nt < 4; ++nt) {
#pragma unroll
                for (int r = 0; r < 4; ++r) {
                    float v = acc[nt][r];
                    v = (wave == 2) ? fast_tanh(v) : fast_sigmoid(v);
                    g2[quad * 4 + r][wave * 64 + nt * 16 + l15] = v;
                }
            }
        }
        __syncthreads();   // B4: g2 ready; h2s MFMA reads done

        // ---- layer-2 epilogue: c2/h2 update; final h2 -> fp32 out ----
        {
            const float4 iv = *(const float4*)&g2[erow][ec2];
            const float4 fv = *(const float4*)&g2[erow][64 + ec2];
            const float4 gv = *(const float4*)&g2[erow][128 + ec2];
            const float4 ov = *(const float4*)&g2[erow][192 + ec2];
            const float ivA[4] = {iv.x, iv.y, iv.z, iv.w};
            const float fvA[4] = {fv.x, fv.y, fv.z, fv.w};
            const float gvA[4] = {gv.x, gv.y, gv.z, gv.w};
            const float ovA[4] = {ov.x, ov.y, ov.z, ov.w};
            float hv[4];
            ushort hi[4], lo[4];
#pragma unroll
            for (int j = 0; j < 4; ++j) {
                const float cn = fvA[j] * c2[j] + ivA[j] * gvA[j];
                c2[j] = cn;
                hv[j] = ovA[j] * fast_tanh(cn);
                hi[j] = f2bf(hv[j]);
                lo[j] = f2bf(hv[j] - bf2f(hi[j]));
            }
            uint2 ph, pl;
            ph.x = (uint)hi[0] | ((uint)hi[1] << 16);
            ph.y = (uint)hi[2] | ((uint)hi[3] << 16);
            pl.x = (uint)lo[0] | ((uint)lo[1] << 16);
            pl.y = (uint)lo[2] | ((uint)lo[3] << 16);
            *(uint2*)&h2s[erow][ec2]      = ph;
            *(uint2*)&h2s[erow][64 + ec2] = pl;
            if (t == T_SEQ - 1) {
                float4 o4 = {hv[0], hv[1], hv[2], hv[3]};
                *(float4*)(out + (size_t)(r0 + erow) * E2 + ec2) = o4;
            }
        }
        __syncthreads();   // B5: h2s(t) ready for next step
    }
}

extern "C" void kernel_launch(void* const* d_in, const int* in_sizes, int n_in,
                              void* d_out, int out_size, void* d_ws, size_t ws_size,
                              hipStream_t stream) {
    lstm_fused<<<32, 256, 0, stream>>>(
        (const float*)d_in[0], (const float*)d_in[1], (const float*)d_in[2],
        (const float*)d_in[3], (const float*)d_in[4], (const float*)d_in[5],
        (const float*)d_in[6], (const float*)d_in[7], (const float*)d_in[8],
        (float*)d_out);
}

// Round 7
// 1340.040 us; speedup vs baseline: 1.9820x; 1.9820x over previous
//
#include <hip/hip_runtime.h>

typedef __attribute__((ext_vector_type(8))) __bf16 bf16x8;
typedef __attribute__((ext_vector_type(4))) float f32x4;

#define MFMA16(a, b, c) __builtin_amdgcn_mfma_f32_16x16x32_bf16(a, b, c, 0, 0, 0)

#define T_SEQ 512
#define F_IN 32
#define H1 128
#define E2 64

__device__ __forceinline__ float bf2f(ushort u) {
    union { uint i; float f; } v; v.i = ((uint)u) << 16; return v.f;
}
__device__ __forceinline__ ushort f2bf(float f) {
    union { float f; uint i; } v; v.f = f;
    uint r = v.i + 0x7fffu + ((v.i >> 16) & 1u);
    return (ushort)(r >> 16);
}
__device__ __forceinline__ float fast_sigmoid(float x) {
    float e = __expf(-x);
    return __builtin_amdgcn_rcpf(1.0f + e);
}
__device__ __forceinline__ float fast_tanh(float x) {
    float e = __expf(-2.0f * x);
    return 2.0f * __builtin_amdgcn_rcpf(1.0f + e) - 1.0f;
}
__device__ __forceinline__ bf16x8 load_w8(const float* p) {
    bf16x8 r;
#pragma unroll
    for (int j = 0; j < 8; ++j) r[j] = (__bf16)p[j];
    return r;
}

// Fused 2-layer LSTM, software-pipelined across waves.
// 32 blocks x 512 threads (8 waves). Block owns 16 batch rows end-to-end.
// Waves 0-3: layer 1 of step t   (wave w owns units [w*32, w*32+32), ALL 4 gates)
// Waves 4-7: layer 2 of step t-1 (wave w-4 owns units [(w-4)*16, +16), ALL 4 gates)
// -> i/f/g/o of a unit live in one lane's accumulators: epilogue in registers,
//    no gate-LDS round-trip, no activation divergence. 2 waves/SIMD (1 L1 + 1 L2).
// Split-precision (hi+lo bf16) for x, h1, h2; fp32 c-state in registers.
// 2 barriers/step. h1 double-buffered in LDS.
__global__ __launch_bounds__(512, 2) void lstm_fused(
    const float* __restrict__ x,      // [512][512][32]
    const float* __restrict__ Wih1,   // [512][32]
    const float* __restrict__ Whh1,   // [512][128]
    const float* __restrict__ bih1,   // [512]
    const float* __restrict__ bhh1,   // [512]
    const float* __restrict__ Wih2,   // [256][128]
    const float* __restrict__ Whh2,   // [256][64]
    const float* __restrict__ bih2,   // [256]
    const float* __restrict__ bhh2,   // [256]
    float* __restrict__ out)          // [512][64] fp32
{
    __shared__ ushort xs [16][72];       // x(t): cols 0..31 hi, 32..63 lo
    __shared__ ushort h1b[2][16][264];   // h1 dbuf: cols 0..127 hi, 128..255 lo
    __shared__ ushort h2s[16][136];      // h2: cols 0..63 hi, 64..127 lo

    const int tid  = threadIdx.x;
    const int wave = tid >> 6;
    const int lane = tid & 63;
    const int l15  = lane & 15;
    const int quad = lane >> 4;
    const int r0   = blockIdx.x * 16;
    const bool isL1 = (wave < 4);
    const int u0 = (wave & 3) * 32;   // L1 unit base (waves 0-3)
    const int u2 = (wave & 3) * 16;   // L2 unit base (waves 4-7)

    // Unified register file for both paths (disjoint per wave, shared slots):
    //  L1: wf[g*8+ut*4+kt] = Whh1 frag (32); wf[32+g*2+ut] = Wih1 frag (8)
    //  L2: wf[g*4+kt] = Wih2 frag (16);      wf[16+g*2+kt] = Whh2 frag (8)
    bf16x8 wf[40];
    float  bias[8];
    float  cst[8];
#pragma unroll
    for (int i = 0; i < 8; ++i) cst[i] = 0.0f;

    if (isL1) {
#pragma unroll
        for (int g = 0; g < 4; ++g)
#pragma unroll
            for (int ut = 0; ut < 2; ++ut) {
                const int n = g * 128 + u0 + ut * 16 + l15;
#pragma unroll
                for (int kt = 0; kt < 4; ++kt)
                    wf[g * 8 + ut * 4 + kt] =
                        load_w8(Whh1 + n * H1 + kt * 32 + quad * 8);
                wf[32 + g * 2 + ut] = load_w8(Wih1 + n * F_IN + quad * 8);
                bias[g * 2 + ut] = bih1[n] + bhh1[n];
            }
    } else {
#pragma unroll
        for (int g = 0; g < 4; ++g) {
            const int n = g * 64 + u2 + l15;
#pragma unroll
            for (int kt = 0; kt < 4; ++kt)
                wf[g * 4 + kt] = load_w8(Wih2 + n * H1 + kt * 32 + quad * 8);
#pragma unroll
            for (int kt = 0; kt < 2; ++kt)
                wf[16 + g * 2 + kt] = load_w8(Whh2 + n * E2 + kt * 32 + quad * 8);
            bias[g] = bih2[n] + bhh2[n];
        }
    }

    // zero h states
    for (int i = tid; i < 2 * 16 * 264; i += 512) ((ushort*)h1b)[i] = 0;
    for (int i = tid; i < 16 * 136;     i += 512) ((ushort*)h2s)[i] = 0;
    __syncthreads();

    f32x4 acc[8];

#pragma unroll 1
    for (int tt = 0; tt <= T_SEQ; ++tt) {
        const int pw = tt & 1;        // h1 write parity (L1 step tt)
        const int pr = pw ^ 1;        // h1 read parity  (= h1(tt-1))

        // ---- stage x(tt): 512 threads x 1 element, hi/lo bf16 ----
        if (tt < T_SEQ) {
            const int row = tid >> 5, col = tid & 31;
            const float v = x[((size_t)(r0 + row) * T_SEQ + tt) * F_IN + col];
            const ushort h = f2bf(v);
            xs[row][col]      = h;
            xs[row][32 + col] = f2bf(v - bf2f(h));
        }
        __syncthreads();   // B1: xs(tt) ready; h1(tt-1), h2(tt-2) stores visible

        if (isL1) {
            if (tt < T_SEQ) {
#pragma unroll
                for (int i = 0; i < 8; ++i)
                    acc[i] = (f32x4){bias[i], bias[i], bias[i], bias[i]};
#pragma unroll
                for (int xt = 0; xt < 2; ++xt) {   // x hi, lo
                    const bf16x8 ax = *(const bf16x8*)&xs[l15][xt * 32 + quad * 8];
#pragma unroll
                    for (int i = 0; i < 8; ++i)
                        acc[i] = MFMA16(ax, wf[32 + i], acc[i]);
                }
#pragma unroll
                for (int kt = 0; kt < 8; ++kt) {   // h1 hi (0-3), lo (4-7)
                    const bf16x8 ah =
                        *(const bf16x8*)&h1b[pr][l15][kt * 32 + quad * 8];
#pragma unroll
                    for (int g = 0; g < 4; ++g)
#pragma unroll
                        for (int ut = 0; ut < 2; ++ut)
                            acc[g * 2 + ut] =
                                MFMA16(ah, wf[g * 8 + ut * 4 + (kt & 3)],
                                       acc[g * 2 + ut]);
                }
            }
        } else {
            if (tt >= 1) {
#pragma unroll
                for (int g = 0; g < 4; ++g)
                    acc[g] = (f32x4){bias[g], bias[g], bias[g], bias[g]};
#pragma unroll
                for (int kt = 0; kt < 8; ++kt) {   // h1 hi+lo, step tt-1
                    const bf16x8 a =
                        *(const bf16x8*)&h1b[pr][l15][kt * 32 + quad * 8];
#pragma unroll
                    for (int g = 0; g < 4; ++g)
                        acc[g] = MFMA16(a, wf[g * 4 + (kt & 3)], acc[g]);
                }
#pragma unroll
                for (int kt = 0; kt < 4; ++kt) {   // h2 hi (0-1), lo (2-3)
                    const bf16x8 a =
                        *(const bf16x8*)&h2s[l15][kt * 32 + quad * 8];
#pragma unroll
                    for (int g = 0; g < 4; ++g)
                        acc[g] = MFMA16(a, wf[16 + g * 2 + (kt & 1)], acc[g]);
                }
            }
        }
        __syncthreads();   // B2: all MFMA reads of h1b[pr], h2s, xs done

        if (isL1) {
            if (tt < T_SEQ) {
                // register epilogue: lane owns (rows quad*4+r, units u0+ut*16+l15)
#pragma unroll
                for (int ut = 0; ut < 2; ++ut)
#pragma unroll
                    for (int r = 0; r < 4; ++r) {
                        const float iv = fast_sigmoid(acc[0 * 2 + ut][r]);
                        const float fv = fast_sigmoid(acc[1 * 2 + ut][r]);
                        const float gv = fast_tanh   (acc[2 * 2 + ut][r]);
                        const float ov = fast_sigmoid(acc[3 * 2 + ut][r]);
                        const float cn = fv * cst[ut * 4 + r] + iv * gv;
                        cst[ut * 4 + r] = cn;
                        const float h = ov * fast_tanh(cn);
                        const ushort hi = f2bf(h);
                        const int row = quad * 4 + r;
                        const int col = u0 + ut * 16 + l15;
                        h1b[pw][row][col]       = hi;
                        h1b[pw][row][128 + col] = f2bf(h - bf2f(hi));
                    }
            }
        } else {
            if (tt >= 1) {
#pragma unroll
                for (int r = 0; r < 4; ++r) {
                    const float iv = fast_sigmoid(acc[0][r]);
                    const float fv = fast_sigmoid(acc[1][r]);
                    const float gv = fast_tanh   (acc[2][r]);
                    const float ov = fast_sigmoid(acc[3][r]);
                    const float cn = fv * cst[r] + iv * gv;
                    cst[r] = cn;
                    const float h = ov * fast_tanh(cn);
                    const ushort hi = f2bf(h);
                    const int row = quad * 4 + r;
                    const int col = u2 + l15;
                    h2s[row][col]      = hi;
                    h2s[row][64 + col] = f2bf(h - bf2f(hi));
                    if (tt == T_SEQ)
                        out[(size_t)(r0 + row) * E2 + col] = h;
                }
            }
        }
    }
}

extern "C" void kernel_launch(void* const* d_in, const int* in_sizes, int n_in,
                              void* d_out, int out_size, void* d_ws, size_t ws_size,
                              hipStream_t stream) {
    lstm_fused<<<32, 512, 0, stream>>>(
        (const float*)d_in[0], (const float*)d_in[1], (const float*)d_in[2],
        (const float*)d_in[3], (const float*)d_in[4], (const float*)d_in[5],
        (const float*)d_in[6], (const float*)d_in[7], (const float*)d_in[8],
        (float*)d_out);
}

// Round 8
// 1061.791 us; speedup vs baseline: 2.5014x; 1.2621x over previous
//
#include <hip/hip_runtime.h>

typedef __attribute__((ext_vector_type(8))) __bf16 bf16x8;
typedef __attribute__((ext_vector_type(4))) float f32x4;

#define MFMA16(a, b, c) __builtin_amdgcn_mfma_f32_16x16x32_bf16(a, b, c, 0, 0, 0)

#define T_SEQ 512
#define F_IN 32
#define H1 128
#define E2 64

__device__ __forceinline__ float bf2f(ushort u) {
    union { uint i; float f; } v; v.i = ((uint)u) << 16; return v.f;
}
__device__ __forceinline__ ushort f2bf(float f) {
    union { float f; uint i; } v; v.f = f;
    uint r = v.i + 0x7fffu + ((v.i >> 16) & 1u);
    return (ushort)(r >> 16);
}
__device__ __forceinline__ float fast_sigmoid(float x) {
    float e = __expf(-x);
    return __builtin_amdgcn_rcpf(1.0f + e);
}
__device__ __forceinline__ float fast_tanh(float x) {
    float e = __expf(-2.0f * x);
    return 2.0f * __builtin_amdgcn_rcpf(1.0f + e) - 1.0f;
}
__device__ __forceinline__ bf16x8 load_w8(const float* p) {
    bf16x8 r;
#pragma unroll
    for (int j = 0; j < 8; ++j) r[j] = (__bf16)p[j];
    return r;
}

// Fused 2-layer LSTM, wave-pipelined, SINGLE barrier per step.
// 32 blocks x 512 threads (8 waves); block owns 16 batch rows end-to-end.
// Waves 0-3: layer 1 of step t; waves 4-7: layer 2 of step t-1.
// All of xs / h1 / h2 double-buffered (parity pw=t&1) -> the only cross-wave
// hazard is "writes of step t visible before reads of step t+1", covered by
// one __syncthreads per step. x(t+1) prefetched into registers during step t.
// Split-precision (hi+lo bf16) for x, h1, h2; fp32 c-state in registers.
__global__ __launch_bounds__(512, 2) void lstm_fused(
    const float* __restrict__ x,      // [512][512][32]
    const float* __restrict__ Wih1,   // [512][32]
    const float* __restrict__ Whh1,   // [512][128]
    const float* __restrict__ bih1,   // [512]
    const float* __restrict__ bhh1,   // [512]
    const float* __restrict__ Wih2,   // [256][128]
    const float* __restrict__ Whh2,   // [256][64]
    const float* __restrict__ bih2,   // [256]
    const float* __restrict__ bhh2,   // [256]
    float* __restrict__ out)          // [512][64] fp32
{
    __shared__ ushort xs [2][16][72];    // x(t): cols 0..31 hi, 32..63 lo
    __shared__ ushort h1b[2][16][264];   // h1: cols 0..127 hi, 128..255 lo
    __shared__ ushort h2b[2][16][136];   // h2: cols 0..63 hi, 64..127 lo

    const int tid  = threadIdx.x;
    const int wave = tid >> 6;
    const int lane = tid & 63;
    const int l15  = lane & 15;
    const int quad = lane >> 4;
    const int r0   = blockIdx.x * 16;
    const bool isL1 = (wave < 4);
    const int u0 = (wave & 3) * 32;   // L1 unit base (waves 0-3)
    const int u2 = (wave & 3) * 16;   // L2 unit base (waves 4-7)

    // Unified register file (disjoint per wave group, shared slots):
    //  L1: wf[g*8+ut*4+kt] = Whh1 frag (32); wf[32+g*2+ut] = Wih1 frag (8)
    //  L2: wf[g*4+kt] = Wih2 frag (16);      wf[16+g*2+kt] = Whh2 frag (8)
    bf16x8 wf[40];
    float  bias[8];
    float  cst[8];
#pragma unroll
    for (int i = 0; i < 8; ++i) cst[i] = 0.0f;

    if (isL1) {
#pragma unroll
        for (int g = 0; g < 4; ++g)
#pragma unroll
            for (int ut = 0; ut < 2; ++ut) {
                const int n = g * 128 + u0 + ut * 16 + l15;
#pragma unroll
                for (int kt = 0; kt < 4; ++kt)
                    wf[g * 8 + ut * 4 + kt] =
                        load_w8(Whh1 + n * H1 + kt * 32 + quad * 8);
                wf[32 + g * 2 + ut] = load_w8(Wih1 + n * F_IN + quad * 8);
                bias[g * 2 + ut] = bih1[n] + bhh1[n];
            }
    } else {
#pragma unroll
        for (int g = 0; g < 4; ++g) {
            const int n = g * 64 + u2 + l15;
#pragma unroll
            for (int kt = 0; kt < 4; ++kt)
                wf[g * 4 + kt] = load_w8(Wih2 + n * H1 + kt * 32 + quad * 8);
#pragma unroll
            for (int kt = 0; kt < 2; ++kt)
                wf[16 + g * 2 + kt] = load_w8(Whh2 + n * E2 + kt * 32 + quad * 8);
            bias[g] = bih2[n] + bhh2[n];
        }
    }

    // zero h states (both parities)
    for (int i = tid; i < 2 * 16 * 264; i += 512) ((ushort*)h1b)[i] = 0;
    for (int i = tid; i < 2 * 16 * 136; i += 512) ((ushort*)h2b)[i] = 0;
    __syncthreads();

    // x prefetch: each thread owns element (row = tid>>5, col = tid&31)
    const int xrow = tid >> 5, xcol = tid & 31;
    const float* xptr = x + ((size_t)(r0 + xrow) * T_SEQ) * F_IN + xcol;
    float xreg = xptr[0];

    f32x4 acc[8];

#pragma unroll 1
    for (int tt = 0; tt <= T_SEQ; ++tt) {
        const int pw = tt & 1;        // write parity (this step's outputs)
        const int pr = pw ^ 1;        // read parity  (previous step's outputs)

        // ---- stage x(tt) from prefetch reg; issue prefetch for tt+1 ----
        if (tt < T_SEQ) {
            const ushort h = f2bf(xreg);
            xs[pw][xrow][xcol]      = h;
            xs[pw][xrow][32 + xcol] = f2bf(xreg - bf2f(h));
            if (tt + 1 < T_SEQ) xreg = xptr[(tt + 1) * F_IN];
        }
        __syncthreads();   // ONE barrier: step-tt writes -> step-tt reads

        if (isL1) {
            if (tt < T_SEQ) {
#pragma unroll
                for (int i = 0; i < 8; ++i)
                    acc[i] = (f32x4){bias[i], bias[i], bias[i], bias[i]};
#pragma unroll
                for (int xt = 0; xt < 2; ++xt) {   // x hi, lo
                    const bf16x8 ax =
                        *(const bf16x8*)&xs[pw][l15][xt * 32 + quad * 8];
#pragma unroll
                    for (int i = 0; i < 8; ++i)
                        acc[i] = MFMA16(ax, wf[32 + i], acc[i]);
                }
#pragma unroll
                for (int kt = 0; kt < 8; ++kt) {   // h1(t-1) hi (0-3), lo (4-7)
                    const bf16x8 ah =
                        *(const bf16x8*)&h1b[pr][l15][kt * 32 + quad * 8];
#pragma unroll
                    for (int g = 0; g < 4; ++g)
#pragma unroll
                        for (int ut = 0; ut < 2; ++ut)
                            acc[g * 2 + ut] =
                                MFMA16(ah, wf[g * 8 + ut * 4 + (kt & 3)],
                                       acc[g * 2 + ut]);
                }
                // register epilogue -> h1b[pw]
#pragma unroll
                for (int ut = 0; ut < 2; ++ut)
#pragma unroll
                    for (int r = 0; r < 4; ++r) {
                        const float iv = fast_sigmoid(acc[0 * 2 + ut][r]);
                        const float fv = fast_sigmoid(acc[1 * 2 + ut][r]);
                        const float gv = fast_tanh   (acc[2 * 2 + ut][r]);
                        const float ov = fast_sigmoid(acc[3 * 2 + ut][r]);
                        const float cn = fv * cst[ut * 4 + r] + iv * gv;
                        cst[ut * 4 + r] = cn;
                        const float h = ov * fast_tanh(cn);
                        const ushort hi = f2bf(h);
                        const int row = quad * 4 + r;
                        const int col = u0 + ut * 16 + l15;
                        h1b[pw][row][col]       = hi;
                        h1b[pw][row][128 + col] = f2bf(h - bf2f(hi));
                    }
            }
        } else {
            if (tt >= 1) {
#pragma unroll
                for (int g = 0; g < 4; ++g)
                    acc[g] = (f32x4){bias[g], bias[g], bias[g], bias[g]};
#pragma unroll
                for (int kt = 0; kt < 8; ++kt) {   // h1(tt-1) hi+lo
                    const bf16x8 a =
                        *(const bf16x8*)&h1b[pr][l15][kt * 32 + quad * 8];
#pragma unroll
                    for (int g = 0; g < 4; ++g)
                        acc[g] = MFMA16(a, wf[g * 4 + (kt & 3)], acc[g]);
                }
#pragma unroll
                for (int kt = 0; kt < 4; ++kt) {   // h2(tt-2) hi (0-1), lo (2-3)
                    const bf16x8 a =
                        *(const bf16x8*)&h2b[pr][l15][kt * 32 + quad * 8];
#pragma unroll
                    for (int g = 0; g < 4; ++g)
                        acc[g] = MFMA16(a, wf[16 + g * 2 + (kt & 1)], acc[g]);
                }
                // register epilogue -> h2b[pw]
#pragma unroll
                for (int r = 0; r < 4; ++r) {
                    const float iv = fast_sigmoid(acc[0][r]);
                    const float fv = fast_sigmoid(acc[1][r]);
                    const float gv = fast_tanh   (acc[2][r]);
                    const float ov = fast_sigmoid(acc[3][r]);
                    const float cn = fv * cst[r] + iv * gv;
                    cst[r] = cn;
                    const float h = ov * fast_tanh(cn);
                    const ushort hi = f2bf(h);
                    const int row = quad * 4 + r;
                    const int col = u2 + l15;
                    h2b[pw][row][col]      = hi;
                    h2b[pw][row][64 + col] = f2bf(h - bf2f(hi));
                    if (tt == T_SEQ)
                        out[(size_t)(r0 + row) * E2 + col] = h;
                }
            }
        }
    }
}

extern "C" void kernel_launch(void* const* d_in, const int* in_sizes, int n_in,
                              void* d_out, int out_size, void* d_ws, size_t ws_size,
                              hipStream_t stream) {
    lstm_fused<<<32, 512, 0, stream>>>(
        (const float*)d_in[0], (const float*)d_in[1], (const float*)d_in[2],
        (const float*)d_in[3], (const float*)d_in[4], (const float*)d_in[5],
        (const float*)d_in[6], (const float*)d_in[7], (const float*)d_in[8],
        (float*)d_out);
}

// Round 9
// 940.448 us; speedup vs baseline: 2.8241x; 1.1290x over previous
//
#include <hip/hip_runtime.h>

typedef __attribute__((ext_vector_type(8))) __bf16 bf16x8;
typedef __attribute__((ext_vector_type(4))) float f32x4;

#define MFMA16(a, b, c) __builtin_amdgcn_mfma_f32_16x16x32_bf16(a, b, c, 0, 0, 0)

#define T_SEQ 512
#define F_IN 32
#define H1 128
#define E2 64
#define ROWS 4          // batch rows per block

__device__ __forceinline__ float bf2f(ushort u) {
    union { uint i; float f; } v; v.i = ((uint)u) << 16; return v.f;
}
__device__ __forceinline__ ushort f2bf(float f) {
    union { float f; uint i; } v; v.f = f;
    uint r = v.i + 0x7fffu + ((v.i >> 16) & 1u);
    return (ushort)(r >> 16);
}
__device__ __forceinline__ float fast_sigmoid(float x) {
    float e = __expf(-x);
    return __builtin_amdgcn_rcpf(1.0f + e);
}
__device__ __forceinline__ float fast_tanh(float x) {
    float e = __expf(-2.0f * x);
    return 2.0f * __builtin_amdgcn_rcpf(1.0f + e) - 1.0f;
}
__device__ __forceinline__ bf16x8 load_w8(const float* p) {
    bf16x8 r;
#pragma unroll
    for (int j = 0; j < 8; ++j) r[j] = (__bf16)p[j];
    return r;
}

// Fused 2-layer LSTM, 128 blocks x 512 threads, 4 batch rows per block.
// MFMA count/block is independent of rows (M=16 tile), so 4x more blocks
// divides per-CU epilogue work by 4 at constant per-SIMD MFMA cost.
// GEMM phase: waves 0-3 = L1 gate-type waves (step t), waves 4-7 = L2 (t-1);
// raw gates (4 valid rows) -> LDS. Epilogue phase: each thread does exactly
// one L1 c-update (tid<256 also one L2 update). 2 barriers/step.
// Split precision (hi+lo bf16) for x/h1/h2; fp32 c in registers.
__global__ __launch_bounds__(512, 2) void lstm_fused(
    const float* __restrict__ x,      // [512][512][32]
    const float* __restrict__ Wih1,   // [512][32]
    const float* __restrict__ Whh1,   // [512][128]
    const float* __restrict__ bih1,   // [512]
    const float* __restrict__ bhh1,   // [512]
    const float* __restrict__ Wih2,   // [256][128]
    const float* __restrict__ Whh2,   // [256][64]
    const float* __restrict__ bih2,   // [256]
    const float* __restrict__ bhh2,   // [256]
    float* __restrict__ out)          // [512][64] fp32
{
    __shared__ ushort xs [16][72];    // x(t): cols 0..31 hi, 32..63 lo
    __shared__ ushort h1s[16][264];   // h1: cols 0..127 hi, 128..255 lo
    __shared__ ushort h2s[16][136];   // h2: cols 0..63 hi, 64..127 lo
    __shared__ float  g1r[ROWS][516]; // raw L1 gates (valid rows only)
    __shared__ float  g2r[ROWS][260]; // raw L2 gates

    const int tid  = threadIdx.x;
    const int wave = tid >> 6;
    const int lane = tid & 63;
    const int l15  = lane & 15;
    const int quad = lane >> 4;
    const int r0   = blockIdx.x * ROWS;
    const bool isL1 = (wave < 4);
    const int gt   = wave & 3;        // gate type (i,f,g,o) owned in GEMM

    // Unified register file (disjoint per wave group):
    //  L1: wf[nt*4+kt] = Whh1 frag (nt<8,kt<4); wf[32+nt] = Wih1 frag
    //  L2: wf[nt*4+kt] = Wih2 frag (nt<4,kt<4); wf[16+nt*2+kt] = Whh2 (kt<2)
    bf16x8 wf[40];
    float  bias[8];

    if (isL1) {
#pragma unroll
        for (int nt = 0; nt < 8; ++nt) {
            const int n = gt * 128 + nt * 16 + l15;
#pragma unroll
            for (int kt = 0; kt < 4; ++kt)
                wf[nt * 4 + kt] = load_w8(Whh1 + n * H1 + kt * 32 + quad * 8);
            wf[32 + nt] = load_w8(Wih1 + n * F_IN + quad * 8);
            bias[nt] = bih1[n] + bhh1[n];
        }
    } else {
#pragma unroll
        for (int nt = 0; nt < 4; ++nt) {
            const int n = gt * 64 + nt * 16 + l15;
#pragma unroll
            for (int kt = 0; kt < 4; ++kt)
                wf[nt * 4 + kt] = load_w8(Wih2 + n * H1 + kt * 32 + quad * 8);
#pragma unroll
            for (int kt = 0; kt < 2; ++kt)
                wf[16 + nt * 2 + kt] = load_w8(Whh2 + n * E2 + kt * 32 + quad * 8);
            bias[nt] = bih2[n] + bhh2[n];
        }
    }

    // zero h states (all 16 rows; rows >= ROWS stay zero forever)
    for (int i = tid; i < 16 * 264; i += 512) ((ushort*)h1s)[i] = 0;
    for (int i = tid; i < 16 * 136; i += 512) ((ushort*)h2s)[i] = 0;
    __syncthreads();

    // per-thread epilogue ownership + fp32 cell state
    const int e1row = tid >> 7, e1u = tid & 127;    // L1: all 512 threads
    const int e2row = tid >> 6, e2u = tid & 63;     // L2: tid < 256
    float c1 = 0.0f, c2 = 0.0f;

    // x prefetch: threads 0..127 own (row = tid>>5, col = tid&31)
    const int xrow = tid >> 5, xcol = tid & 31;
    const float* xptr = x + ((size_t)(r0 + (xrow & 3)) * T_SEQ) * F_IN + xcol;
    float xreg = (tid < 128) ? xptr[0] : 0.0f;

    f32x4 acc[8];

#pragma unroll 1
    for (int tt = 0; tt <= T_SEQ; ++tt) {
        // ---- stage x(tt), prefetch x(tt+1) ----
        if (tt < T_SEQ && tid < 128) {
            const ushort h = f2bf(xreg);
            xs[xrow][xcol]      = h;
            xs[xrow][32 + xcol] = f2bf(xreg - bf2f(h));
            if (tt + 1 < T_SEQ) xreg = xptr[(tt + 1) * F_IN];
        }
        __syncthreads();   // B1: xs(tt), h1(tt-1), h2(tt-2) ready

        // ---- GEMM phase ----
        if (isL1) {
            if (tt < T_SEQ) {
#pragma unroll
                for (int nt = 0; nt < 8; ++nt)
                    acc[nt] = (f32x4){bias[nt], bias[nt], bias[nt], bias[nt]};
#pragma unroll
                for (int xt = 0; xt < 2; ++xt) {   // x hi, lo
                    const bf16x8 ax = *(const bf16x8*)&xs[l15][xt * 32 + quad * 8];
#pragma unroll
                    for (int nt = 0; nt < 8; ++nt)
                        acc[nt] = MFMA16(ax, wf[32 + nt], acc[nt]);
                }
#pragma unroll
                for (int kt = 0; kt < 8; ++kt) {   // h1 hi (0-3), lo (4-7)
                    const bf16x8 ah = *(const bf16x8*)&h1s[l15][kt * 32 + quad * 8];
#pragma unroll
                    for (int nt = 0; nt < 8; ++nt)
                        acc[nt] = MFMA16(ah, wf[nt * 4 + (kt & 3)], acc[nt]);
                }
                if (quad == 0) {   // rows 0..3 are the valid rows
#pragma unroll
                    for (int nt = 0; nt < 8; ++nt)
#pragma unroll
                        for (int r = 0; r < ROWS; ++r)
                            g1r[r][gt * 128 + nt * 16 + l15] = acc[nt][r];
                }
            }
        } else {
            if (tt >= 1) {
#pragma unroll
                for (int nt = 0; nt < 4; ++nt)
                    acc[nt] = (f32x4){bias[nt], bias[nt], bias[nt], bias[nt]};
#pragma unroll
                for (int kt = 0; kt < 8; ++kt) {   // h1 hi+lo
                    const bf16x8 a = *(const bf16x8*)&h1s[l15][kt * 32 + quad * 8];
#pragma unroll
                    for (int nt = 0; nt < 4; ++nt)
                        acc[nt] = MFMA16(a, wf[nt * 4 + (kt & 3)], acc[nt]);
                }
#pragma unroll
                for (int kt = 0; kt < 4; ++kt) {   // h2 hi (0-1), lo (2-3)
                    const bf16x8 a = *(const bf16x8*)&h2s[l15][kt * 32 + quad * 8];
#pragma unroll
                    for (int nt = 0; nt < 4; ++nt)
                        acc[nt] = MFMA16(a, wf[16 + nt * 2 + (kt & 1)], acc[nt]);
                }
                if (quad == 0) {
#pragma unroll
                    for (int nt = 0; nt < 4; ++nt)
#pragma unroll
                        for (int r = 0; r < ROWS; ++r)
                            g2r[r][gt * 64 + nt * 16 + l15] = acc[nt][r];
                }
            }
        }
        __syncthreads();   // B2: raw gates ready; h/x MFMA reads done

        // ---- epilogue phase: 1 L1 update/thread; 1 L2 update for tid<256 ----
        if (tt < T_SEQ) {
            const float iv = fast_sigmoid(g1r[e1row][e1u]);
            const float fv = fast_sigmoid(g1r[e1row][128 + e1u]);
            const float gv = fast_tanh   (g1r[e1row][256 + e1u]);
            const float ov = fast_sigmoid(g1r[e1row][384 + e1u]);
            const float cn = fv * c1 + iv * gv;
            c1 = cn;
            const float h = ov * fast_tanh(cn);
            const ushort hi = f2bf(h);
            h1s[e1row][e1u]       = hi;
            h1s[e1row][128 + e1u] = f2bf(h - bf2f(hi));
        }
        if (tid < 256 && tt >= 1) {
            const float iv = fast_sigmoid(g2r[e2row][e2u]);
            const float fv = fast_sigmoid(g2r[e2row][64 + e2u]);
            const float gv = fast_tanh   (g2r[e2row][128 + e2u]);
            const float ov = fast_sigmoid(g2r[e2row][192 + e2u]);
            const float cn = fv * c2 + iv * gv;
            c2 = cn;
            const float h = ov * fast_tanh(cn);
            const ushort hi = f2bf(h);
            h2s[e2row][e2u]      = hi;
            h2s[e2row][64 + e2u] = f2bf(h - bf2f(hi));
            if (tt == T_SEQ)
                out[(size_t)(r0 + e2row) * E2 + e2u] = h;
        }
    }
}

extern "C" void kernel_launch(void* const* d_in, const int* in_sizes, int n_in,
                              void* d_out, int out_size, void* d_ws, size_t ws_size,
                              hipStream_t stream) {
    lstm_fused<<<128, 512, 0, stream>>>(
        (const float*)d_in[0], (const float*)d_in[1], (const float*)d_in[2],
        (const float*)d_in[3], (const float*)d_in[4], (const float*)d_in[5],
        (const float*)d_in[6], (const float*)d_in[7], (const float*)d_in[8],
        (float*)d_out);
}

// Round 10
// 935.076 us; speedup vs baseline: 2.8404x; 1.0057x over previous
//
#include <hip/hip_runtime.h>

typedef __attribute__((ext_vector_type(8))) __bf16 bf16x8;
typedef __attribute__((ext_vector_type(4))) float f32x4;

#define MFMA16(a, b, c) __builtin_amdgcn_mfma_f32_16x16x32_bf16(a, b, c, 0, 0, 0)

#define T_SEQ 512
#define F_IN 32
#define H1 128
#define E2 64
#define ROWS 4          // batch rows per block

__device__ __forceinline__ float bf2f(ushort u) {
    union { uint i; float f; } v; v.i = ((uint)u) << 16; return v.f;
}
__device__ __forceinline__ ushort f2bf(float f) {
    union { float f; uint i; } v; v.f = f;
    uint r = v.i + 0x7fffu + ((v.i >> 16) & 1u);
    return (ushort)(r >> 16);
}
__device__ __forceinline__ float fast_sigmoid(float x) {
    float e = __expf(-x);
    return __builtin_amdgcn_rcpf(1.0f + e);
}
__device__ __forceinline__ float fast_tanh(float x) {
    float e = __expf(-2.0f * x);
    return 2.0f * __builtin_amdgcn_rcpf(1.0f + e) - 1.0f;
}
__device__ __forceinline__ bf16x8 load_w8(const float* p) {
    bf16x8 r;
#pragma unroll
    for (int j = 0; j < 8; ++j) r[j] = (__bf16)p[j];
    return r;
}

// Fused 2-layer LSTM, 128 blocks x 512 threads, 4 batch rows per block.
// IDENTICAL to round-9 kernel except __launch_bounds__(512, 1):
// round 9's (512,2) capped VGPRs at 128, spilling the 160-VGPR weight
// fragment file to scratch (WRITE_SIZE 8.5MB = spill stores; per-step scratch
// reloads were the hidden ~3000 cyc/step). 2 waves/SIMD allows 256 VGPR/wave;
// need ~230 -> weights become truly register-resident.
__global__ __launch_bounds__(512, 1) void lstm_fused(
    const float* __restrict__ x,      // [512][512][32]
    const float* __restrict__ Wih1,   // [512][32]
    const float* __restrict__ Whh1,   // [512][128]
    const float* __restrict__ bih1,   // [512]
    const float* __restrict__ bhh1,   // [512]
    const float* __restrict__ Wih2,   // [256][128]
    const float* __restrict__ Whh2,   // [256][64]
    const float* __restrict__ bih2,   // [256]
    const float* __restrict__ bhh2,   // [256]
    float* __restrict__ out)          // [512][64] fp32
{
    __shared__ ushort xs [16][72];    // x(t): cols 0..31 hi, 32..63 lo
    __shared__ ushort h1s[16][264];   // h1: cols 0..127 hi, 128..255 lo
    __shared__ ushort h2s[16][136];   // h2: cols 0..63 hi, 64..127 lo
    __shared__ float  g1r[ROWS][516]; // raw L1 gates (valid rows only)
    __shared__ float  g2r[ROWS][260]; // raw L2 gates

    const int tid  = threadIdx.x;
    const int wave = tid >> 6;
    const int lane = tid & 63;
    const int l15  = lane & 15;
    const int quad = lane >> 4;
    const int r0   = blockIdx.x * ROWS;
    const bool isL1 = (wave < 4);
    const int gt   = wave & 3;        // gate type (i,f,g,o) owned in GEMM

    // Unified register file (disjoint per wave group):
    //  L1: wf[nt*4+kt] = Whh1 frag (nt<8,kt<4); wf[32+nt] = Wih1 frag
    //  L2: wf[nt*4+kt] = Wih2 frag (nt<4,kt<4); wf[16+nt*2+kt] = Whh2 (kt<2)
    bf16x8 wf[40];
    float  bias[8];

    if (isL1) {
#pragma unroll
        for (int nt = 0; nt < 8; ++nt) {
            const int n = gt * 128 + nt * 16 + l15;
#pragma unroll
            for (int kt = 0; kt < 4; ++kt)
                wf[nt * 4 + kt] = load_w8(Whh1 + n * H1 + kt * 32 + quad * 8);
            wf[32 + nt] = load_w8(Wih1 + n * F_IN + quad * 8);
            bias[nt] = bih1[n] + bhh1[n];
        }
    } else {
#pragma unroll
        for (int nt = 0; nt < 4; ++nt) {
            const int n = gt * 64 + nt * 16 + l15;
#pragma unroll
            for (int kt = 0; kt < 4; ++kt)
                wf[nt * 4 + kt] = load_w8(Wih2 + n * H1 + kt * 32 + quad * 8);
#pragma unroll
            for (int kt = 0; kt < 2; ++kt)
                wf[16 + nt * 2 + kt] = load_w8(Whh2 + n * E2 + kt * 32 + quad * 8);
            bias[nt] = bih2[n] + bhh2[n];
        }
    }

    // zero h states (all 16 rows; rows >= ROWS stay zero forever)
    for (int i = tid; i < 16 * 264; i += 512) ((ushort*)h1s)[i] = 0;
    for (int i = tid; i < 16 * 136; i += 512) ((ushort*)h2s)[i] = 0;
    __syncthreads();

    // per-thread epilogue ownership + fp32 cell state
    const int e1row = tid >> 7, e1u = tid & 127;    // L1: all 512 threads
    const int e2row = tid >> 6, e2u = tid & 63;     // L2: tid < 256
    float c1 = 0.0f, c2 = 0.0f;

    // x prefetch: threads 0..127 own (row = tid>>5, col = tid&31)
    const int xrow = tid >> 5, xcol = tid & 31;
    const float* xptr = x + ((size_t)(r0 + (xrow & 3)) * T_SEQ) * F_IN + xcol;
    float xreg = (tid < 128) ? xptr[0] : 0.0f;

    f32x4 acc[8];

#pragma unroll 1
    for (int tt = 0; tt <= T_SEQ; ++tt) {
        // ---- stage x(tt), prefetch x(tt+1) ----
        if (tt < T_SEQ && tid < 128) {
            const ushort h = f2bf(xreg);
            xs[xrow][xcol]      = h;
            xs[xrow][32 + xcol] = f2bf(xreg - bf2f(h));
            if (tt + 1 < T_SEQ) xreg = xptr[(tt + 1) * F_IN];
        }
        __syncthreads();   // B1: xs(tt), h1(tt-1), h2(tt-2) ready

        // ---- GEMM phase ----
        if (isL1) {
            if (tt < T_SEQ) {
#pragma unroll
                for (int nt = 0; nt < 8; ++nt)
                    acc[nt] = (f32x4){bias[nt], bias[nt], bias[nt], bias[nt]};
#pragma unroll
                for (int xt = 0; xt < 2; ++xt) {   // x hi, lo
                    const bf16x8 ax = *(const bf16x8*)&xs[l15][xt * 32 + quad * 8];
#pragma unroll
                    for (int nt = 0; nt < 8; ++nt)
                        acc[nt] = MFMA16(ax, wf[32 + nt], acc[nt]);
                }
#pragma unroll
                for (int kt = 0; kt < 8; ++kt) {   // h1 hi (0-3), lo (4-7)
                    const bf16x8 ah = *(const bf16x8*)&h1s[l15][kt * 32 + quad * 8];
#pragma unroll
                    for (int nt = 0; nt < 8; ++nt)
                        acc[nt] = MFMA16(ah, wf[nt * 4 + (kt & 3)], acc[nt]);
                }
                if (quad == 0) {   // rows 0..3 are the valid rows
#pragma unroll
                    for (int nt = 0; nt < 8; ++nt)
#pragma unroll
                        for (int r = 0; r < ROWS; ++r)
                            g1r[r][gt * 128 + nt * 16 + l15] = acc[nt][r];
                }
            }
        } else {
            if (tt >= 1) {
#pragma unroll
                for (int nt = 0; nt < 4; ++nt)
                    acc[nt] = (f32x4){bias[nt], bias[nt], bias[nt], bias[nt]};
#pragma unroll
                for (int kt = 0; kt < 8; ++kt) {   // h1 hi+lo
                    const bf16x8 a = *(const bf16x8*)&h1s[l15][kt * 32 + quad * 8];
#pragma unroll
                    for (int nt = 0; nt < 4; ++nt)
                        acc[nt] = MFMA16(a, wf[nt * 4 + (kt & 3)], acc[nt]);
                }
#pragma unroll
                for (int kt = 0; kt < 4; ++kt) {   // h2 hi (0-1), lo (2-3)
                    const bf16x8 a = *(const bf16x8*)&h2s[l15][kt * 32 + quad * 8];
#pragma unroll
                    for (int nt = 0; nt < 4; ++nt)
                        acc[nt] = MFMA16(a, wf[16 + nt * 2 + (kt & 1)], acc[nt]);
                }
                if (quad == 0) {
#pragma unroll
                    for (int nt = 0; nt < 4; ++nt)
#pragma unroll
                        for (int r = 0; r < ROWS; ++r)
                            g2r[r][gt * 64 + nt * 16 + l15] = acc[nt][r];
                }
            }
        }
        __syncthreads();   // B2: raw gates ready; h/x MFMA reads done

        // ---- epilogue phase: 1 L1 update/thread; 1 L2 update for tid<256 ----
        if (tt < T_SEQ) {
            const float iv = fast_sigmoid(g1r[e1row][e1u]);
            const float fv = fast_sigmoid(g1r[e1row][128 + e1u]);
            const float gv = fast_tanh   (g1r[e1row][256 + e1u]);
            const float ov = fast_sigmoid(g1r[e1row][384 + e1u]);
            const float cn = fv * c1 + iv * gv;
            c1 = cn;
            const float h = ov * fast_tanh(cn);
            const ushort hi = f2bf(h);
            h1s[e1row][e1u]       = hi;
            h1s[e1row][128 + e1u] = f2bf(h - bf2f(hi));
        }
        if (tid < 256 && tt >= 1) {
            const float iv = fast_sigmoid(g2r[e2row][e2u]);
            const float fv = fast_sigmoid(g2r[e2row][64 + e2u]);
            const float gv = fast_tanh   (g2r[e2row][128 + e2u]);
            const float ov = fast_sigmoid(g2r[e2row][192 + e2u]);
            const float cn = fv * c2 + iv * gv;
            c2 = cn;
            const float h = ov * fast_tanh(cn);
            const ushort hi = f2bf(h);
            h2s[e2row][e2u]      = hi;
            h2s[e2row][64 + e2u] = f2bf(h - bf2f(hi));
            if (tt == T_SEQ)
                out[(size_t)(r0 + e2row) * E2 + e2u] = h;
        }
    }
}

extern "C" void kernel_launch(void* const* d_in, const int* in_sizes, int n_in,
                              void* d_out, int out_size, void* d_ws, size_t ws_size,
                              hipStream_t stream) {
    lstm_fused<<<128, 512, 0, stream>>>(
        (const float*)d_in[0], (const float*)d_in[1], (const float*)d_in[2],
        (const float*)d_in[3], (const float*)d_in[4], (const float*)d_in[5],
        (const float*)d_in[6], (const float*)d_in[7], (const float*)d_in[8],
        (float*)d_out);
}